// Round 4
// baseline (220.514 us; speedup 1.0000x reference)
//
#include <hip/hip_runtime.h>

// PositionalEncoding: x[B,S,N,F] -> out[B,S,N,F+2], B=64,S=4096,N=25,F=3.
// out[...,0:3]=x; out[...,3]=||x_next-x||; out[...,4]=nan_to_num(acos(dot/(|x||x_next|)))
// x_next = step s+1 (self-pair at s=S-1).
//
// R1-R3 post-mortem: three different structures all 186-193us; harness fixed
// work (512MB ws poison ~78us + d_out poison + d_in restore + tiny memsets)
// dominates dur_us; kernel portion ~33-40us vs 31us traffic floor (210 MB).
// R4: zero-barrier zero-LDS structure (R1's win) + full float4 vectorization:
// 4 groups/thread -> 3x float4 loads (48B/thread, aligned), 5x float4 stores
// (80B/thread, aligned); only the 12 next-step floats are scalar (L1 hits -
// same block's float4 stream covers that region at +300B).

constexpr int Nc = 25, Sc = 4096;
constexpr int BLOCK = 256;
constexpr int GPT = 4;                                        // groups per thread
constexpr long TOTAL_G = 64L * Sc * Nc;                       // 6,553,600
constexpr int NUM_BLOCKS = (int)(TOTAL_G / (BLOCK * GPT));    // 6400

__global__ __launch_bounds__(BLOCK) void pe_kernel(const float* __restrict__ x,
                                                   float* __restrict__ out) {
    const int t = blockIdx.x * BLOCK + threadIdx.x;
    const int g0 = t * GPT;

    // own x vectors: 12 consecutive floats = 3 aligned float4
    const float4* __restrict__ xv = (const float4*)(x + 12L * t);
    float4 a0 = xv[0], a1 = xv[1], a2 = xv[2];
    float a[12] = {a0.x, a0.y, a0.z, a0.w,
                   a1.x, a1.y, a1.z, a1.w,
                   a2.x, a2.y, a2.z, a2.w};

    // row/s bookkeeping: one magic-div, then carry per group
    const int row0 = g0 / Nc;
    const int rem0 = g0 - row0 * Nc;

    float o[GPT * 5];
    #pragma unroll
    for (int j = 0; j < GPT; ++j) {
        int g = g0 + j;
        int row = row0 + ((rem0 + j) >= Nc ? 1 : 0);
        bool self = ((row & (Sc - 1)) == Sc - 1);     // s == S-1 -> pair with itself
        long ng = self ? (long)g : (long)g + Nc;      // always in-bounds

        const float* __restrict__ yp = x + 3 * ng;
        float x0 = a[3 * j], x1 = a[3 * j + 1], x2 = a[3 * j + 2];
        float y0 = yp[0], y1 = yp[1], y2 = yp[2];

        float d0 = y0 - x0, d1 = y1 - x1, d2 = y2 - x2;
        float dist = sqrtf(d0 * d0 + d1 * d1 + d2 * d2);

        float dot = x0 * y0 + x1 * y1 + x2 * y2;
        float nx = sqrtf(x0 * x0 + x1 * x1 + x2 * x2);
        float ny = sqrtf(y0 * y0 + y1 * y1 + y2 * y2);
        float ang = acosf(dot / (nx * ny));           // NaN when |ratio|>1 from rounding
        if (isnan(ang)) ang = 0.0f;                   // jnp.nan_to_num

        o[j * 5]     = x0;
        o[j * 5 + 1] = x1;
        o[j * 5 + 2] = x2;
        o[j * 5 + 3] = dist;
        o[j * 5 + 4] = ang;
    }

    // 20 consecutive floats out = 5 aligned float4
    float4* __restrict__ ov = (float4*)(out + 20L * t);
    ov[0] = make_float4(o[0],  o[1],  o[2],  o[3]);
    ov[1] = make_float4(o[4],  o[5],  o[6],  o[7]);
    ov[2] = make_float4(o[8],  o[9],  o[10], o[11]);
    ov[3] = make_float4(o[12], o[13], o[14], o[15]);
    ov[4] = make_float4(o[16], o[17], o[18], o[19]);
}

extern "C" void kernel_launch(void* const* d_in, const int* in_sizes, int n_in,
                              void* d_out, int out_size, void* d_ws, size_t ws_size,
                              hipStream_t stream) {
    const float* x = (const float*)d_in[0];
    float* out = (float*)d_out;
    pe_kernel<<<NUM_BLOCKS, BLOCK, 0, stream>>>(x, out);
}